// Round 16
// 521.684 us; speedup vs baseline: 1.2617x; 1.0089x over previous
//
#include <hip/hip_runtime.h>
#include <hip/hip_bf16.h>
#include <math.h>

typedef __hip_bfloat16 bf16;
typedef __attribute__((ext_vector_type(8))) short short8v;   // 8 bf16 (4 VGPRs)
typedef __attribute__((ext_vector_type(4))) short short4v;   // 4 bf16 (2 VGPRs)
typedef __attribute__((ext_vector_type(4))) float float4v;   // 4 fp32 acc
#define MFMA16 __builtin_amdgcn_mfma_f32_16x16x32_bf16

__device__ __forceinline__ float us2f(unsigned short u) {
  union { unsigned u; float f; } c; c.u = ((unsigned)u) << 16; return c.f;
}
__device__ __forceinline__ unsigned short f2us(float f) {
  return __bfloat16_as_ushort(__float2bfloat16(f));
}

// fp32 x . fp32 w, K % 8 == 0, 16B-aligned
__device__ __forceinline__ float dot_ff(const float* __restrict__ x,
                                        const float* __restrict__ w, int K) {
  const float4* xp = reinterpret_cast<const float4*>(x);
  const float4* wp = reinterpret_cast<const float4*>(w);
  float acc = 0.f;
  const int n = K >> 2;
  for (int i = 0; i < n; ++i) {
    float4 a = xp[i], b = wp[i];
    acc += a.x*b.x + a.y*b.y + a.z*b.z + a.w*b.w;
  }
  return acc;
}

// native-exp sigmoid / tanh (clamped; serial-path hot in GRU)
__device__ __forceinline__ float sigm(float x) { return 1.f / (1.f + __expf(-x)); }
__device__ __forceinline__ float tanh_fast(float x) {
  x = fminf(fmaxf(x, -15.f), 15.f);
  float e = __expf(2.f * x);
  return (e - 1.f) / (e + 1.f);
}

// ---------------------------------------------------------------------------
__global__ void k_canary(float* __restrict__ out) {
  out[blockIdx.x * 256 + threadIdx.x] = 100.0f;
}

// ---------------------------------------------------------------------------
// One-shot: convert MFMA-consumed weights to bf16 in ws.
// ---------------------------------------------------------------------------
__global__ __launch_bounds__(256) void k_cvt(
    const float* __restrict__ a_in_w, const float* __restrict__ t_in_w,
    const float* __restrict__ t_out_w, const float* __restrict__ t_ff1w,
    const float* __restrict__ t_ff2w, const float* __restrict__ a_out_w,
    unsigned short* __restrict__ awb, unsigned short* __restrict__ twb,
    unsigned short* __restrict__ pwb, unsigned short* __restrict__ f1wb,
    unsigned short* __restrict__ f2wb, unsigned short* __restrict__ awb2)
{
  int i = blockIdx.x * 256 + threadIdx.x;
  if (i < 49152)  awb[i] = f2us(a_in_w[i]);
  if (i < 786432) twb[i] = f2us(t_in_w[i]);
  if (i < 262144) pwb[i] = f2us(t_out_w[i]);
  if (i < 524288) f1wb[i] = f2us(t_ff1w[i]);
  if (i < 524288) f2wb[i] = f2us(t_ff2w[i]);
  if (i < 16384)  awb2[i] = f2us(a_out_w[i]);
}

// ---------------------------------------------------------------------------
// GRU weight prep: row-major bf16 copies. whhb [dir][768][256],
// wihb [dir][768][128] (for gi GEMM).
// ---------------------------------------------------------------------------
__global__ __launch_bounds__(256) void k_gru_wb(
    const float* __restrict__ wih_f, const float* __restrict__ whh_f,
    const float* __restrict__ wih_b, const float* __restrict__ whh_b,
    unsigned short* __restrict__ whhb, unsigned short* __restrict__ wihb)
{
  int i = blockIdx.x * 256 + threadIdx.x;   // < 393216
  if (i >= 393216) return;
  int dir = i / 196608, r = i % 196608;
  whhb[i] = f2us((dir ? whh_b : whh_f)[r]);
  if (r < 98304) wihb[dir * 98304 + r] = f2us((dir ? wih_b : wih_f)[r]);
}

// ---------------------------------------------------------------------------
// QKV precompute over the VOCAB. qkt[49689][256] = q,k with bias;
// vt[49689][128] = v with bias. M=32 rows/block, grid 1553.
// ---------------------------------------------------------------------------
__global__ __launch_bounds__(256, 2) void k_qkvpre(
    const float* __restrict__ emb, const unsigned short* __restrict__ awb,
    const float* __restrict__ in_b,
    unsigned short* __restrict__ qkt, unsigned short* __restrict__ vt)
{
  const int row0 = blockIdx.x * 32, tid = threadIdx.x;
  __shared__ alignas(16) unsigned short xs[32 * 136];
  for (int i = tid; i < 1024; i += 256) {
    int t = i >> 5, c4 = (i & 31) << 2;
    int grow = row0 + t; if (grow > 49688) grow = 49688;
    float4 e4 = *reinterpret_cast<const float4*>(emb + (size_t)grow * 128 + c4);
    short4v s; s[0] = f2us(e4.x); s[1] = f2us(e4.y); s[2] = f2us(e4.z); s[3] = f2us(e4.w);
    *reinterpret_cast<short4v*>(xs + t * 136 + c4) = s;
  }
  __syncthreads();
  const int lane = tid & 63, wave = tid >> 6;
  const int l15 = lane & 15, quad = lane >> 4;
  short8v af[2][4];
#pragma unroll
  for (int mt = 0; mt < 2; ++mt)
#pragma unroll
    for (int kc = 0; kc < 4; ++kc)
      af[mt][kc] = *reinterpret_cast<const short8v*>(
          xs + (mt * 16 + l15) * 136 + kc * 32 + quad * 8);
  for (int ni = 0; ni < 6; ++ni) {
    const int j = (wave + ni * 4) * 16 + l15;
    const unsigned short* wrow = awb + (size_t)j * 128;
    float4v acc0 = {0.f, 0.f, 0.f, 0.f}, acc1 = {0.f, 0.f, 0.f, 0.f};
#pragma unroll
    for (int kc = 0; kc < 4; ++kc) {
      short8v bfr = *reinterpret_cast<const short8v*>(wrow + kc * 32 + quad * 8);
      acc0 = MFMA16(af[0][kc], bfr, acc0, 0, 0, 0);
      acc1 = MFMA16(af[1][kc], bfr, acc1, 0, 0, 0);
    }
    const float bj = in_b[j];
#pragma unroll
    for (int r = 0; r < 4; ++r) {
      int g0 = row0 + quad * 4 + r, g1 = g0 + 16;
      if (j < 256) {
        if (g0 <= 49688) qkt[(size_t)g0 * 256 + j] = f2us(acc0[r] + bj);
        if (g1 <= 49688) qkt[(size_t)g1 * 256 + j] = f2us(acc1[r] + bj);
      } else {
        int jj = j - 256;
        if (g0 <= 49688) vt[(size_t)g0 * 128 + jj] = f2us(acc0[r] + bj);
        if (g1 <= 49688) vt[(size_t)g1 * 128 + jj] = f2us(acc1[r] + bj);
      }
    }
  }
}

// ---------------------------------------------------------------------------
// Stage 1: gather precomputed q/k/vT + fused attention + proj-then-mean.
// vTb padded to stride 40 (80 B): kills the 32-way bank conflicts the
// stride-32 (64 B) transpose scatter caused (bank = (row*20 + t/2) % 32,
// period-8 spread; 16B reads stay aligned since 80 % 16 == 0).
// LDS: qb 8704 (O overlay) + kb 8704 (P overlay) + vTb 10240 = 27,648 B
// -> 5 blocks/CU.
// ---------------------------------------------------------------------------
__global__ __launch_bounds__(256, 5) void k_order_attn(
    const int* __restrict__ oh, const unsigned short* __restrict__ qkt,
    const unsigned short* __restrict__ vt,
    const unsigned short* __restrict__ awb2, const float* __restrict__ out_b,
    unsigned short* __restrict__ oeb)
{
  const int bo = blockIdx.x;            // 0..8191
  const int tid = threadIdx.x;
  __shared__ alignas(16) unsigned short qb[32 * 136];     // q -> O
  __shared__ alignas(16) unsigned short kb[32 * 136];     // k -> P [128][32]
  __shared__ alignas(16) unsigned short vTb[128 * 40];    // vT[d][t], stride 40
  unsigned short* ob = qb;
  unsigned short* pb = kb;

  const int lane = tid & 63, wave = tid >> 6;
  const int l15 = lane & 15, quad = lane >> 4;

  // gather q,k (16B/lane, 512B contiguous per token)
  for (int i = tid; i < 1024; i += 256) {
    int t = i >> 5, c8 = (i & 31) << 3;
    int id = oh[bo * 32 + t];
    short8v v8 = *reinterpret_cast<const short8v*>(qkt + (size_t)id * 256 + c8);
    if (c8 < 128) *reinterpret_cast<short8v*>(qb + t * 136 + c8) = v8;
    else          *reinterpret_cast<short8v*>(kb + t * 136 + (c8 - 128)) = v8;
  }
  // gather v, transpose into vTb (stride 40) via scalar LDS scatter
  for (int i = tid; i < 512; i += 256) {
    int t = i >> 4, c8 = (i & 15) << 3;
    int id = oh[bo * 32 + t];
    short8v v8 = *reinterpret_cast<const short8v*>(vt + (size_t)id * 128 + c8);
#pragma unroll
    for (int j2 = 0; j2 < 8; ++j2) vTb[(c8 + j2) * 40 + t] = v8[j2];
  }
  __syncthreads();
  // ---- FUSED: scores + exp + PV + ones-rowsum + O write (wave = head) ----
  {
    const int h = wave;
    const float scale1 = 0.17677669529663687f;            // 1/sqrt(32)
    short8v qf[2], kf[2];
#pragma unroll
    for (int mt = 0; mt < 2; ++mt)
      qf[mt] = *reinterpret_cast<const short8v*>(qb + (mt * 16 + l15) * 136 + h * 32 + quad * 8);
#pragma unroll
    for (int nt = 0; nt < 2; ++nt)
      kf[nt] = *reinterpret_cast<const short8v*>(kb + (nt * 16 + l15) * 136 + h * 32 + quad * 8);
    float4v sacc[2][2];
#pragma unroll
    for (int mt = 0; mt < 2; ++mt)
#pragma unroll
      for (int nt = 0; nt < 2; ++nt) {
        sacc[mt][nt] = (float4v){0.f, 0.f, 0.f, 0.f};
        sacc[mt][nt] = MFMA16(qf[mt], kf[nt], sacc[mt][nt], 0, 0, 0);
      }
    __syncthreads();                     // all qb/kb reg-reads done -> P/O writes ok
    // P = exp(s) (no max subtraction: |s| <~ 2, safe)
#pragma unroll
    for (int mt = 0; mt < 2; ++mt)
#pragma unroll
      for (int r = 0; r < 4; ++r) {
        float e0 = __expf(sacc[mt][0][r] * scale1);
        float e1 = __expf(sacc[mt][1][r] * scale1);
        int row = h * 32 + mt * 16 + quad * 4 + r;
        pb[row * 32 + l15] = f2us(e0);
        pb[row * 32 + 16 + l15] = f2us(e1);
      }
    // ones fragment for rowsum MFMA
    short8v ones;
#pragma unroll
    for (int i = 0; i < 8; ++i) ones[i] = (short)0x3F80;  // bf16 1.0
    short8v pf[2], vf[2];
#pragma unroll
    for (int mt = 0; mt < 2; ++mt)
      pf[mt] = *reinterpret_cast<const short8v*>(pb + (h * 32 + mt * 16 + l15) * 32 + quad * 8);
    float4v sums[2];
#pragma unroll
    for (int mt = 0; mt < 2; ++mt) {
      sums[mt] = (float4v){0.f, 0.f, 0.f, 0.f};
      sums[mt] = MFMA16(pf[mt], ones, sums[mt], 0, 0, 0);  // rowsums in C layout
    }
#pragma unroll
    for (int nt = 0; nt < 2; ++nt)
      vf[nt] = *reinterpret_cast<const short8v*>(vTb + (h * 32 + nt * 16 + l15) * 40 + quad * 8);
    float4v oacc[2][2];
#pragma unroll
    for (int mt = 0; mt < 2; ++mt)
#pragma unroll
      for (int nt = 0; nt < 2; ++nt) {
        oacc[mt][nt] = (float4v){0.f, 0.f, 0.f, 0.f};
        oacc[mt][nt] = MFMA16(pf[mt], vf[nt], oacc[mt][nt], 0, 0, 0);
      }
    // write O bf16 into ob (qb overlay): this wave's head-col stripe
#pragma unroll
    for (int mt = 0; mt < 2; ++mt)
#pragma unroll
      for (int r = 0; r < 4; ++r) {
        int t = mt * 16 + quad * 4 + r;
        float inv = 1.f / sums[mt][r];
#pragma unroll
        for (int nt = 0; nt < 2; ++nt)
          ob[t * 136 + h * 32 + nt * 16 + l15] = f2us(oacc[mt][nt][r] * inv);
      }
  }
  __syncthreads();
  // ---- out-proj MFMA: proj[t][j] = O[t][.] . W[j][.]; then mean over t ----
  {
    float4v acc[2][2];
#pragma unroll
    for (int mt = 0; mt < 2; ++mt)
#pragma unroll
      for (int nt = 0; nt < 2; ++nt) acc[mt][nt] = (float4v){0.f, 0.f, 0.f, 0.f};
#pragma unroll
    for (int kc = 0; kc < 4; ++kc) {
      short8v af0 = *reinterpret_cast<const short8v*>(ob + l15 * 136 + kc * 32 + quad * 8);
      short8v af1 = *reinterpret_cast<const short8v*>(ob + (16 + l15) * 136 + kc * 32 + quad * 8);
#pragma unroll
      for (int nt = 0; nt < 2; ++nt) {
        int j = (wave * 2 + nt) * 16 + l15;
        short8v bfr = *reinterpret_cast<const short8v*>(awb2 + (size_t)j * 128 + kc * 32 + quad * 8);
        acc[0][nt] = MFMA16(af0, bfr, acc[0][nt], 0, 0, 0);
        acc[1][nt] = MFMA16(af1, bfr, acc[1][nt], 0, 0, 0);
      }
    }
#pragma unroll
    for (int nt = 0; nt < 2; ++nt) {
      float part = 0.f;
#pragma unroll
      for (int mt = 0; mt < 2; ++mt)
#pragma unroll
        for (int r = 0; r < 4; ++r) part += acc[mt][nt][r];
      part += __shfl_xor(part, 16);
      part += __shfl_xor(part, 32);
      if (quad == 0) {
        int j = (wave * 2 + nt) * 16 + l15;
        oeb[(size_t)bo * 128 + j] = f2us(part * (1.f / 32.f) + out_b[j]);
      }
    }
  }
}

// ---------------------------------------------------------------------------
// gi GEMM (MFMA): gi[8192][1536] bf16 = oe @ wih^T (both dirs). oe is bf16.
// ---------------------------------------------------------------------------
__global__ __launch_bounds__(256, 2) void k_gru_gi(
    const unsigned short* __restrict__ oeb, const unsigned short* __restrict__ wihb,
    unsigned short* __restrict__ gi)
{
  const int row0 = blockIdx.x * 32, tid = threadIdx.x;
  __shared__ alignas(16) unsigned short xs[32 * 136];
  for (int i = tid; i < 512; i += 256) {
    int t = i >> 4, c8 = (i & 15) << 3;
    *reinterpret_cast<short8v*>(xs + t * 136 + c8) =
        *reinterpret_cast<const short8v*>(oeb + (size_t)(row0 + t) * 128 + c8);
  }
  __syncthreads();
  const int lane = tid & 63, wave = tid >> 6;
  const int l15 = lane & 15, quad = lane >> 4;
  short8v af[2][4];
#pragma unroll
  for (int mt = 0; mt < 2; ++mt)
#pragma unroll
    for (int kc = 0; kc < 4; ++kc)
      af[mt][kc] = *reinterpret_cast<const short8v*>(
          xs + (mt * 16 + l15) * 136 + kc * 32 + quad * 8);
  for (int ni = 0; ni < 24; ++ni) {
    int col = (wave + ni * 4) * 16 + l15;
    const unsigned short* wrow = wihb + (size_t)col * 128;
    float4v a0 = {0.f,0.f,0.f,0.f}, a1 = {0.f,0.f,0.f,0.f};
#pragma unroll
    for (int kc = 0; kc < 4; ++kc) {
      short8v bfr = *reinterpret_cast<const short8v*>(wrow + kc * 32 + quad * 8);
      a0 = MFMA16(af[0][kc], bfr, a0, 0, 0, 0);
      a1 = MFMA16(af[1][kc], bfr, a1, 0, 0, 0);
    }
#pragma unroll
    for (int r = 0; r < 4; ++r) {
      gi[(size_t)(row0 + quad * 4 + r) * 1536 + col] = f2us(a0[r]);
      gi[(size_t)(row0 + quad * 4 + r + 16) * 1536 + col] = f2us(a1[r]);
    }
  }
}

// ---------------------------------------------------------------------------
// GRU recurrence via MFMA. 2 batches/block, grid (128,2) = 256 blocks,
// 512 threads (8 waves). whh register-resident. gi prefetched.
// LDS: hb 8448 + pg 6176 = 14,624 B.
// ---------------------------------------------------------------------------
__global__ __launch_bounds__(512, 2) void k_gru_rec(
    const unsigned short* __restrict__ gi, const unsigned short* __restrict__ whhb,
    const float* __restrict__ bih_f, const float* __restrict__ bhh_f,
    const float* __restrict__ bih_b, const float* __restrict__ bhh_b,
    float* __restrict__ g)
{
  const int b0 = blockIdx.x * 2, dir = blockIdx.y;
  const int tid = threadIdx.x;           // 0..511
  const unsigned short* wb = whhb + (size_t)dir * 196608;   // [768][256] bf16
  const float* bih = dir ? bih_b : bih_f;
  const float* bhh = dir ? bhh_b : bhh_f;
  __shared__ alignas(16) unsigned short hb[16 * 264];   // h bf16 (A operand)
  __shared__ float pg[2 * 772];                         // gh fp32 (rows 0-1)
  const int lane = tid & 63, wave = tid >> 6;
  const int l15 = lane & 15, quad = lane >> 4;
  const int j = tid & 255, mb = tid >> 8;               // pointwise: (m=mb, j)
  const float bir = bih[j], biz = bih[256 + j], bin_ = bih[512 + j];
  const float bhr = bhh[j], bhz = bhh[256 + j], bhn  = bhh[512 + j];
  short8v wf[6][8];
  int cols[6];
#pragma unroll
  for (int ni = 0; ni < 6; ++ni) {
    cols[ni] = (wave + ni * 8) * 16 + l15;
#pragma unroll
    for (int kc = 0; kc < 8; ++kc)
      wf[ni][kc] = *reinterpret_cast<const short8v*>(
          wb + (size_t)cols[ni] * 256 + kc * 32 + quad * 8);
  }
  for (int i = tid; i < 16 * 264; i += 512) hb[i] = 0;
  int tcur = dir ? 31 : 0;
  size_t gbase = ((size_t)(b0 + mb) * 32 + tcur) * 1536 + dir * 768;
  float gr = us2f(gi[gbase + j]);
  float gz = us2f(gi[gbase + 256 + j]);
  float gn = us2f(gi[gbase + 512 + j]);
  __syncthreads();
  for (int s = 0; s < 32; ++s) {
    float4v acc[6];
#pragma unroll
    for (int ni = 0; ni < 6; ++ni) acc[ni] = (float4v){0.f, 0.f, 0.f, 0.f};
#pragma unroll
    for (int kc = 0; kc < 8; ++kc) {
      short8v af = *reinterpret_cast<const short8v*>(hb + l15 * 264 + kc * 32 + quad * 8);
#pragma unroll
      for (int ni = 0; ni < 6; ++ni)
        acc[ni] = MFMA16(af, wf[ni][kc], acc[ni], 0, 0, 0);
    }
    if (quad == 0) {
#pragma unroll
      for (int ni = 0; ni < 6; ++ni) {
        pg[cols[ni]] = acc[ni][0];
        pg[772 + cols[ni]] = acc[ni][1];
      }
    }
    float gr2 = 0.f, gz2 = 0.f, gn2 = 0.f;
    if (s < 31) {
      int t2 = dir ? (30 - s) : (s + 1);
      size_t gb2 = ((size_t)(b0 + mb) * 32 + t2) * 1536 + dir * 768;
      gr2 = us2f(gi[gb2 + j]);
      gz2 = us2f(gi[gb2 + 256 + j]);
      gn2 = us2f(gi[gb2 + 512 + j]);
    }
    __syncthreads();
    {
      const int tt = dir ? (31 - s) : s;
      float hprev = us2f(hb[mb * 264 + j]);
      float r = sigm(gr + bir + pg[mb * 772 + j] + bhr);
      float z = sigm(gz + biz + pg[mb * 772 + 256 + j] + bhz);
      float n = tanh_fast(gn + bin_ + r * (pg[mb * 772 + 512 + j] + bhn));
      float nh = (1.f - z) * n + z * hprev;
      hb[mb * 264 + j] = f2us(nh);
      g[((size_t)(b0 + mb) * 32 + tt) * 512 + dir * 256 + j] = nh;
    }
    gr = gr2; gz = gz2; gn = gn2;
    __syncthreads();
  }
}

// ---------------------------------------------------------------------------
// Stage 3 fused attention, one block per (b, head). x staged in K=128
// quarter-chunks (xs3 8,704 B) -> LDS 36,352 B -> 4 blocks/CU.
// ---------------------------------------------------------------------------
__global__ __launch_bounds__(256, 4) void k_mha2f(
    const float* __restrict__ g, const unsigned short* __restrict__ twb,
    const float* __restrict__ Bv, float* __restrict__ attn)
{
  const int b = blockIdx.x, h = blockIdx.y, tid = threadIdx.x;
  __shared__ alignas(16) unsigned short xs3[32 * 136];     // x chunk; P overlay
  __shared__ alignas(16) unsigned short qk[2 * 32 * 136];
  __shared__ alignas(16) unsigned short vT[128 * 40];      // vT[d][k]
  unsigned short* qs = qk;
  unsigned short* ks = qk + 32 * 136;
  unsigned short* pb = xs3;                                // P bf16 [32][32]
  const int lane = tid & 63, wave = tid >> 6;
  const int l15 = lane & 15, quad = lane >> 4;

  int wrowi[6];
#pragma unroll
  for (int ni = 0; ni < 6; ++ni) {
    int idx = (wave + ni * 4) * 16 + l15;
    int m = idx >> 7, dd = idx & 127;
    wrowi[ni] = m * 512 + h * 128 + dd;
  }
  float4v acc[6][2];
#pragma unroll
  for (int ni = 0; ni < 6; ++ni)
#pragma unroll
    for (int mt = 0; mt < 2; ++mt) acc[ni][mt] = (float4v){0.f, 0.f, 0.f, 0.f};

  for (int ck = 0; ck < 4; ++ck) {
    __syncthreads();
    for (int i = tid; i < 1024; i += 256) {                // x quarter load
      int t = i >> 5, c4 = (i & 31) << 2;
      float4 e4 = *reinterpret_cast<const float4*>(
          g + (size_t)b * 16384 + t * 512 + ck * 128 + c4);
      short4v s; s[0] = f2us(e4.x); s[1] = f2us(e4.y); s[2] = f2us(e4.z); s[3] = f2us(e4.w);
      *reinterpret_cast<short4v*>(xs3 + t * 136 + c4) = s;
    }
    __syncthreads();
    short8v af2[2][4];
#pragma unroll
    for (int mt = 0; mt < 2; ++mt)
#pragma unroll
      for (int u = 0; u < 4; ++u)
        af2[mt][u] = *reinterpret_cast<const short8v*>(
            xs3 + (mt * 16 + l15) * 136 + u * 32 + quad * 8);
#pragma unroll
    for (int ni = 0; ni < 6; ++ni) {
      const unsigned short* wrow = twb + (size_t)wrowi[ni] * 512 + ck * 128;
#pragma unroll
      for (int u = 0; u < 4; ++u) {
        short8v bfr = *reinterpret_cast<const short8v*>(wrow + u * 32 + quad * 8);
        acc[ni][0] = MFMA16(af2[0][u], bfr, acc[ni][0], 0, 0, 0);
        acc[ni][1] = MFMA16(af2[1][u], bfr, acc[ni][1], 0, 0, 0);
      }
    }
  }
  __syncthreads();                                         // xs3 reads done
#pragma unroll
  for (int ni = 0; ni < 6; ++ni) {
    int idx = (wave + ni * 4) * 16 + l15;
    int m = idx >> 7, dd = idx & 127;
    float bj = Bv[wrowi[ni]];
    if (m < 2) {
      unsigned short* dst = (m == 0) ? qs : ks;
#pragma unroll
      for (int r = 0; r < 4; ++r) {
        int t0 = quad * 4 + r;
        dst[t0 * 136 + dd] = f2us(acc[ni][0][r] + bj);
        dst[(t0 + 16) * 136 + dd] = f2us(acc[ni][1][r] + bj);
      }
    } else {
      short4v s0, s1;
#pragma unroll
      for (int r = 0; r < 4; ++r) { s0[r] = f2us(acc[ni][0][r] + bj); s1[r] = f2us(acc[ni][1][r] + bj); }
      *reinterpret_cast<short4v*>(vT + dd * 40 + quad * 4) = s0;
      *reinterpret_cast<short4v*>(vT + dd * 40 + 16 + quad * 4) = s1;
    }
  }
  __syncthreads();
  // ---- scores MFMA -> P = exp(s) bf16 directly (no max: |s| <~ 7) ----
  {
    const float scale2 = 0.08838834764831845f;            // 1/sqrt(128)
    const int mt = wave >> 1, nt = wave & 1;
    float4v a = {0.f, 0.f, 0.f, 0.f};
#pragma unroll
    for (int kc = 0; kc < 4; ++kc) {
      short8v qf = *reinterpret_cast<const short8v*>(qs + (mt * 16 + l15) * 136 + kc * 32 + quad * 8);
      short8v kf = *reinterpret_cast<const short8v*>(ks + (nt * 16 + l15) * 136 + kc * 32 + quad * 8);
      a = MFMA16(qf, kf, a, 0, 0, 0);
    }
#pragma unroll
    for (int r = 0; r < 4; ++r) {
      int row = mt * 16 + quad * 4 + r;
      pb[row * 32 + nt * 16 + l15] = f2us(__expf(a[r] * scale2));
    }
  }
  __syncthreads();
  // ---- PV MFMA + ones-rowsum; scale by 1/sum in epilogue ----
  {
    short8v ones;
#pragma unroll
    for (int i = 0; i < 8; ++i) ones[i] = (short)0x3F80;  // bf16 1.0
    short8v pf[2], vf[2];
#pragma unroll
    for (int mt = 0; mt < 2; ++mt)
      pf[mt] = *reinterpret_cast<const short8v*>(pb + (mt * 16 + l15) * 32 + quad * 8);
    float4v sums[2];
#pragma unroll
    for (int mt = 0; mt < 2; ++mt) {
      sums[mt] = (float4v){0.f, 0.f, 0.f, 0.f};
      sums[mt] = MFMA16(pf[mt], ones, sums[mt], 0, 0, 0);
    }
#pragma unroll
    for (int ntl = 0; ntl < 2; ++ntl)
      vf[ntl] = *reinterpret_cast<const short8v*>(vT + ((2 * wave + ntl) * 16 + l15) * 40 + quad * 8);
    float4v oacc[2][2];
#pragma unroll
    for (int mt = 0; mt < 2; ++mt)
#pragma unroll
      for (int ntl = 0; ntl < 2; ++ntl) {
        oacc[mt][ntl] = (float4v){0.f, 0.f, 0.f, 0.f};
        oacc[mt][ntl] = MFMA16(pf[mt], vf[ntl], oacc[mt][ntl], 0, 0, 0);
      }
#pragma unroll
    for (int mt = 0; mt < 2; ++mt)
#pragma unroll
      for (int r = 0; r < 4; ++r) {
        int q = mt * 16 + quad * 4 + r;
        float inv = 1.f / sums[mt][r];
#pragma unroll
        for (int ntl = 0; ntl < 2; ++ntl)
          attn[((size_t)b * 32 + q) * 512 + h * 128 + (2 * wave + ntl) * 16 + l15] =
              oacc[mt][ntl][r] * inv;
      }
  }
}

// ---------------------------------------------------------------------------
// proj GEMM raw, M=32/block (grid 256, halves pwb streaming), 1024 threads
// (16 waves = 50% occ). Writes praw = X @ W^T + bias (fp32); residual+LN
// done by k_resln. LDS: xs 33,280 B.
// ---------------------------------------------------------------------------
__global__ __launch_bounds__(1024, 1) void k_proj(
    const float* __restrict__ X, const unsigned short* __restrict__ Wb,
    const float* __restrict__ bias, float* __restrict__ praw)
{
  const int row0 = blockIdx.x * 32, tid = threadIdx.x;
  __shared__ alignas(16) unsigned short xs[32 * 520];
  const int lane = tid & 63, wave = tid >> 6;             // wave 0..15
  const int l15 = lane & 15, quad = lane >> 4;
  for (int i = tid; i < 4096; i += 1024) {
    int t = i >> 7, c4 = (i & 127) << 2;
    float4 e4 = *reinterpret_cast<const float4*>(X + (size_t)(row0 + t) * 512 + c4);
    short4v s; s[0] = f2us(e4.x); s[1] = f2us(e4.y); s[2] = f2us(e4.z); s[3] = f2us(e4.w);
    *reinterpret_cast<short4v*>(xs + t * 520 + c4) = s;
  }
  __syncthreads();
#pragma unroll
  for (int ni = 0; ni < 2; ++ni) {
    const int col = (wave + ni * 16) * 16 + l15;
    const unsigned short* wrow = Wb + (size_t)col * 512;
    float4v a0 = {0.f,0.f,0.f,0.f}, a1 = {0.f,0.f,0.f,0.f};
#pragma unroll
    for (int kc = 0; kc < 16; ++kc) {
      short8v b = *reinterpret_cast<const short8v*>(wrow + kc * 32 + quad * 8);
      short8v x0 = *reinterpret_cast<const short8v*>(xs + l15 * 520 + kc * 32 + quad * 8);
      short8v x1 = *reinterpret_cast<const short8v*>(xs + (16 + l15) * 520 + kc * 32 + quad * 8);
      a0 = MFMA16(x0, b, a0, 0, 0, 0);
      a1 = MFMA16(x1, b, a1, 0, 0, 0);
    }
    const float bj = bias[col];
#pragma unroll
    for (int r = 0; r < 4; ++r) {
      praw[(size_t)(row0 + quad * 4 + r) * 512 + col] = a0[r] + bj;
      praw[(size_t)(row0 + 16 + quad * 4 + r) * 512 + col] = a1[r] + bj;
    }
  }
}

// ---------------------------------------------------------------------------
// FF pair, M=32/block (grid 256), 1024 threads (16 waves = 50% occ).
// 4 chunks of 256 f1-cols. f1 chunk in LDS, ff2 accumulates each K-chunk
// into persistent regs. Writes yraw (fp32).
// LDS: xs 33,280 + f1c 16,896 = 50,176 B.
// ---------------------------------------------------------------------------
__global__ __launch_bounds__(1024, 1) void k_ff(
    const float* __restrict__ X, const unsigned short* __restrict__ W1,
    const float* __restrict__ b1, const unsigned short* __restrict__ W2,
    const float* __restrict__ b2, float* __restrict__ yraw)
{
  const int row0 = blockIdx.x * 32, tid = threadIdx.x;
  __shared__ alignas(16) unsigned short xs[32 * 520];     // X bf16 [32][520]
  __shared__ alignas(16) unsigned short f1c[32 * 264];    // f1 chunk [32][264]
  const int lane = tid & 63, wave = tid >> 6;             // wave 0..15
  const int l15 = lane & 15, quad = lane >> 4;
  for (int i = tid; i < 4096; i += 1024) {                // X load (float4)
    int t = i >> 7, c4 = (i & 127) << 2;
    float4 e4 = *reinterpret_cast<const float4*>(X + (size_t)(row0 + t) * 512 + c4);
    short4v s; s[0] = f2us(e4.x); s[1] = f2us(e4.y); s[2] = f2us(e4.z); s[3] = f2us(e4.w);
    *reinterpret_cast<short4v*>(xs + t * 520 + c4) = s;
  }
  __syncthreads();
  float4v acc2[2][2];                                     // ff2 accum (persist)
#pragma unroll
  for (int mt = 0; mt < 2; ++mt)
#pragma unroll
    for (int ni = 0; ni < 2; ++ni) acc2[mt][ni] = (float4v){0.f,0.f,0.f,0.f};
  int cols2[2];
#pragma unroll
  for (int ni = 0; ni < 2; ++ni) cols2[ni] = (wave + ni * 16) * 16 + l15;

  for (int ck = 0; ck < 4; ++ck) {                        // 4 chunks of 256 f1-cols
    // ---- ff1 for this chunk: col = ck*256 + wave*16 + l15 ----
    {
      const int col = ck * 256 + wave * 16 + l15;
      const unsigned short* wrow = W1 + (size_t)col * 512;
      float4v a0 = {0.f,0.f,0.f,0.f}, a1 = {0.f,0.f,0.f,0.f};
#pragma unroll
      for (int kc = 0; kc < 16; ++kc) {
        short8v b = *reinterpret_cast<const short8v*>(wrow + kc * 32 + quad * 8);
        short8v x0 = *reinterpret_cast<const short8v*>(xs + l15 * 520 + kc * 32 + quad * 8);
        short8v x1 = *reinterpret_cast<const short8v*>(xs + (16 + l15) * 520 + kc * 32 + quad * 8);
        a0 = MFMA16(x0, b, a0, 0, 0, 0);
        a1 = MFMA16(x1, b, a1, 0, 0, 0);
      }
      const float bj = b1[col];
      const int cl = wave * 16 + l15;                     // chunk-local col
#pragma unroll
      for (int r = 0; r < 4; ++r) {
        f1c[(quad * 4 + r) * 264 + cl] = f2us(fmaxf(a0[r] + bj, 0.f));
        f1c[(16 + quad * 4 + r) * 264 + cl] = f2us(fmaxf(a1[r] + bj, 0.f));
      }
    }
    __syncthreads();
    // ---- ff2 accumulate this K-chunk (256 elems = 8 kc) ----
#pragma unroll
    for (int ni = 0; ni < 2; ++ni) {
      const unsigned short* wrow2 = W2 + (size_t)cols2[ni] * 1024 + ck * 256;
#pragma unroll
      for (int kc = 0; kc < 8; ++kc) {
        short8v b = *reinterpret_cast<const short8v*>(wrow2 + kc * 32 + quad * 8);
        short8v a0 = *reinterpret_cast<const short8v*>(f1c + l15 * 264 + kc * 32 + quad * 8);
        short8v a1 = *reinterpret_cast<const short8v*>(f1c + (16 + l15) * 264 + kc * 32 + quad * 8);
        acc2[0][ni] = MFMA16(a0, b, acc2[0][ni], 0, 0, 0);
        acc2[1][ni] = MFMA16(a1, b, acc2[1][ni], 0, 0, 0);
      }
    }
    __syncthreads();                                      // f1c reusable
  }
  // ---- epilogue: yraw = ff2 + bias (fp32) ----
#pragma unroll
  for (int mt = 0; mt < 2; ++mt)
#pragma unroll
    for (int ni = 0; ni < 2; ++ni) {
      int col = cols2[ni];
      float bj = b2[col];
#pragma unroll
      for (int r = 0; r < 4; ++r)
        yraw[(size_t)(row0 + mt * 16 + quad * 4 + r) * 512 + col] = acc2[mt][ni][r] + bj;
    }
}

// ---------------------------------------------------------------------------
// residual + LN: Y = LN(yraw + res). M=16/block, grid 512, 256 threads.
// ---------------------------------------------------------------------------
__global__ __launch_bounds__(256, 2) void k_resln(
    const float* __restrict__ yraw, const float* __restrict__ res,
    const float* __restrict__ gam, const float* __restrict__ bet,
    float* __restrict__ Y)
{
  const int row0 = blockIdx.x * 16, tid = threadIdx.x;
  __shared__ float ys[16 * 516];
  for (int i = tid; i < 16 * 512; i += 256) {
    int t = i >> 9, c = i & 511;
    ys[t * 516 + c] = yraw[(size_t)(row0 + t) * 512 + c] +
                      res[(size_t)(row0 + t) * 512 + c];
  }
  __syncthreads();
  {
    int row = tid >> 4, l16 = tid & 15;
    const float* yr = ys + row * 516;
    float part = 0.f;
#pragma unroll
    for (int k = 0; k < 32; ++k) part += yr[l16 + 16 * k];
#pragma unroll
    for (int off = 8; off; off >>= 1) part += __shfl_xor(part, off, 16);
    float mean = part * (1.f / 512.f);
    float var = 0.f;
#pragma unroll
    for (int k = 0; k < 32; ++k) { float d = yr[l16 + 16 * k] - mean; var += d * d; }
#pragma unroll
    for (int off = 8; off; off >>= 1) var += __shfl_xor(var, off, 16);
    float rs = rsqrtf(var * (1.f / 512.f) + 1e-5f);
    for (int k = 0; k < 32; ++k) {
      int c = l16 + 16 * k;
      Y[(size_t)(row0 + row) * 512 + c] = (yr[c] - mean) * rs * gam[c] + bet[c];
    }
  }
}

// ---------------------------------------------------------------------------
// Final: mean-pool, temporal MLP, concat, classifier, LN, relu -> fp32
// ---------------------------------------------------------------------------
__global__ __launch_bounds__(256) void k_final(
    const float* __restrict__ g2,
    const float* __restrict__ db, const float* __restrict__ dsl,
    const float* __restrict__ te1_w, const float* __restrict__ te1_b,
    const float* __restrict__ l1g, const float* __restrict__ l1b,
    const float* __restrict__ te2_w, const float* __restrict__ te2_b,
    const float* __restrict__ l2g, const float* __restrict__ l2b,
    const float* __restrict__ c_w, const float* __restrict__ c_b,
    const float* __restrict__ clg, const float* __restrict__ clb,
    float* __restrict__ out)
{
  const int b = blockIdx.x, tid = threadIdx.x;
  __shared__ float cat[640];
  __shared__ float t1[64];
  __shared__ float t2[128];
  __shared__ float pre[256];
  __shared__ float red[256];
  __shared__ float st[2];
  for (int i = tid; i < 512; i += 256) {
    float acc = 0.f;
#pragma unroll
    for (int t = 0; t < 32; ++t) acc += g2[((size_t)b * 32 + t) * 512 + i];
    cat[i] = acc * (1.f / 32.f);
  }
  if (tid == 0) {
    float s = 0.f;
    for (int i = 0; i < 31; ++i) s += db[b * 31 + i];
    st[0] = s / 31.f;
    st[1] = dsl[b];
  }
  __syncthreads();
  const float f0 = st[0], f1v = st[1];
  if (tid < 64)
    t1[tid] = f0 * te1_w[tid * 2] + f1v * te1_w[tid * 2 + 1] + te1_b[tid];
  __syncthreads();
  if (tid == 0) {
    float m = 0.f; for (int i = 0; i < 64; ++i) m += t1[i]; m *= (1.f / 64.f);
    float v = 0.f; for (int i = 0; i < 64; ++i) { float d = t1[i] - m; v += d * d; }
    st[0] = m; st[1] = rsqrtf(v * (1.f / 64.f) + 1e-5f);
  }
  __syncthreads();
  if (tid < 64) {
    float v = (t1[tid] - st[0]) * st[1] * l1g[tid] + l1b[tid];
    t1[tid] = fmaxf(v, 0.f);
  }
  __syncthreads();
  if (tid < 128)
    t2[tid] = dot_ff(t1, te2_w + (size_t)tid * 64, 64) + te2_b[tid];
  __syncthreads();
  if (tid == 0) {
    float m = 0.f; for (int i = 0; i < 128; ++i) m += t2[i]; m *= (1.f / 128.f);
    float v = 0.f; for (int i = 0; i < 128; ++i) { float d = t2[i] - m; v += d * d; }
    st[0] = m; st[1] = rsqrtf(v * (1.f / 128.f) + 1e-5f);
  }
  __syncthreads();
  if (tid < 128) {
    float v = (t2[tid] - st[0]) * st[1] * l2g[tid] + l2b[tid];
    cat[512 + tid] = fmaxf(v, 0.f);
  }
  __syncthreads();
  pre[tid] = dot_ff(cat, c_w + (size_t)tid * 640, 640) + c_b[tid];
  red[tid] = pre[tid];
  __syncthreads();
  for (int s = 128; s > 0; s >>= 1) { if (tid < s) red[tid] += red[tid + s]; __syncthreads(); }
  const float m = red[0] * (1.f / 256.f);
  __syncthreads();
  const float d = pre[tid] - m;
  red[tid] = d * d;
  __syncthreads();
  for (int s = 128; s > 0; s >>= 1) { if (tid < s) red[tid] += red[tid + s]; __syncthreads(); }
  const float rs = rsqrtf(red[0] * (1.f / 256.f) + 1e-5f);
  float v = d * rs * clg[tid] + clb[tid];
  out[(size_t)b * 256 + tid] = fmaxf(v, 0.f);
}

// ---------------------------------------------------------------------------
extern "C" void kernel_launch(void* const* d_in, const int* in_sizes, int n_in,
                              void* d_out, int out_size, void* d_ws, size_t ws_size,
                              hipStream_t stream) {
  (void)in_sizes; (void)n_in; (void)out_size; (void)ws_size;
  const int*   oh     = (const int*)  d_in[0];
  const float* db     = (const float*)d_in[1];
  const float* dsl    = (const float*)d_in[2];
  const float* emb    = (const float*)d_in[3];
  const float* a_in_w = (const float*)d_in[4];
  const float* a_in_b = (const float*)d_in[5];
  const float* a_out_w= (const float*)d_in[6];
  const float* a_out_b= (const float*)d_in[7];
  const float* wih_f  = (const float*)d_in[8];
  const float* whh_f  = (const float*)d_in[9];
  const float* bih_f  = (const float*)d_in[10];
  const float* bhh_f  = (const float*)d_in[11];
  const float* wih_b  = (const float*)d_in[12];
  const float* whh_b  = (const float*)d_in[13];
  const float* bih_b  = (const float*)d_in[14];
  const float* bhh_b  = (const float*)d_in[15];
  const float* t_in_w = (const float*)d_in[16];
  const float* t_in_b = (const float*)d_in[17];
  const float* t_out_w= (const float*)d_in[18];
  const float* t_out_b= (const float*)d_in[19];
  const float* t_ln1g = (const float*)d_in[20];
  const float* t_ln1b = (const float*)d_in[21];
  const float* t_ff1w = (const float*)d_in[22];
  const float* t_ff1b = (const float*)d_in[23];
  const float* t_ff2w = (const float*)d_in[24];
  const float* t_ff2b = (const float*)d_in[25];
  const float* t_ln2g = (const float*)d_in[26];
  const float* t_ln2b = (const float*)d_in[27];
  const float* te1_w  = (const float*)d_in[28];
  const float* te1_b  = (const float*)d_in[29];
  const float* tl1g   = (const float*)d_in[30];
  const float* tl1b   = (const float*)d_in[31];
  const float* te2_w  = (const float*)d_in[32];
  const float* te2_b  = (const float*)d_in[33];
  const float* tl2g   = (const float*)d_in[34];
  const float* tl2b   = (const float*)d_in[35];
  const float* c_w    = (const float*)d_in[36];
  const float* c_b    = (const float*)d_in[37];
  const float* clng   = (const float*)d_in[38];
  const float* clnb   = (const float*)d_in[39];

  float* ws = (float*)d_ws;
  // Workspace (float slots), max index 17,391,616 (~69.6 MB):
  //   A [0,        524288):  oeb bf16 [8192][128]
  //   B [1048576,  5242880): qkt bf16 (dead after order_attn) -> g fp32
  //       -> yraw fp32 (after resln#1; g dead)
  //   C [5242880,  9437184): attn fp32; g1 resln#1 in-place; g2 resln#2
  //   D [9437184,  9633792): whhb bf16 [2][768][256]
  //   D2[9633792,  9732096): wihb bf16 [2][768][128]
  //   D3[9732096,  9740288): awb2 bf16 [128*128]
  //   E [10027008,10051584): awb bf16 [384*128]
  //   F [10051584,10444800): twb bf16 [1536*512]
  //   G [10444800,10575872): pwb bf16 [512*512]
  //   G2[10575872,10838016): f1wb bf16 [1024*512]
  //   G3[10838016,11100160): f2wb bf16 [512*1024]
  //   H [11100160,17391616): vt bf16 -> gi bf16 (dead after gru_rec)
  //       -> praw fp32 [8192][512] (proj raw)
  unsigned short* oeb  = (unsigned short*)ws;
  unsigned short* qkt  = (unsigned short*)(ws + 1048576);
  float* g    = ws + 1048576;                           // over dead qkt
  float* yraw = ws + 1048576;                           // over dead g (post-resln#1)
  float* attn = ws + 5242880;
  float* g1   = attn;                                   // in-place resln#1 out
  float* g2   = attn;                                   // in-place resln#2 out
  unsigned short* whhb = (unsigned short*)(ws + 9437184);
  unsigned short* wihb = (unsigned short*)(ws + 9633792);
  unsigned short* awb2 = (unsigned short*)(ws + 9732096);
  unsigned short* awb  = (unsigned short*)(ws + 10027008);
  unsigned short* twb  = (unsigned short*)(ws + 10051584);
  unsigned short* pwb  = (unsigned short*)(ws + 10444800);
  unsigned short* f1wb = (unsigned short*)(ws + 10575872);
  unsigned short* f2wb = (unsigned short*)(ws + 10838016);
  unsigned short* vt   = (unsigned short*)(ws + 11100160);
  unsigned short* gi   = (unsigned short*)(ws + 11100160); // over dead vt
  float* praw = ws + 11100160;                          // over dead gi

  k_canary<<<256, 256, 0, stream>>>((float*)d_out);
  k_cvt<<<3072, 256, 0, stream>>>(a_in_w, t_in_w, t_out_w, t_ff1w, t_ff2w, a_out_w,
                                  awb, twb, pwb, f1wb, f2wb, awb2);
  k_gru_wb<<<1536, 256, 0, stream>>>(wih_f, whh_f, wih_b, whh_b, whhb, wihb);
  k_qkvpre<<<1553, 256, 0, stream>>>(emb, awb, a_in_b, qkt, vt);
  k_order_attn<<<8192, 256, 0, stream>>>(oh, qkt, vt, awb2, a_out_b, oeb);
  k_gru_gi<<<256, 256, 0, stream>>>(oeb, wihb, gi);
  k_gru_rec<<<dim3(128, 2), 512, 0, stream>>>(gi, whhb, bih_f, bhh_f, bih_b, bhh_b, g);
  k_mha2f<<<dim3(256, 4), 256, 0, stream>>>(g, twb, t_in_b, attn);
  k_proj<<<256, 1024, 0, stream>>>(attn, pwb, t_out_b, praw);
  k_resln<<<512, 256, 0, stream>>>(praw, g, t_ln1g, t_ln1b, g1);
  k_ff<<<256, 1024, 0, stream>>>(g1, f1wb, t_ff1b, f2wb, t_ff2b, yraw);
  k_resln<<<512, 256, 0, stream>>>(yraw, g1, t_ln2g, t_ln2b, g2);
  k_final<<<256, 256, 0, stream>>>(g2, db, dsl, te1_w, te1_b, tl1g, tl1b,
                                   te2_w, te2_b, tl2g, tl2b, c_w, c_b, clng, clnb,
                                   (float*)d_out);
}

// Round 17
// 520.656 us; speedup vs baseline: 1.2641x; 1.0020x over previous
//
#include <hip/hip_runtime.h>
#include <hip/hip_bf16.h>
#include <math.h>

typedef __hip_bfloat16 bf16;
typedef __attribute__((ext_vector_type(8))) short short8v;   // 8 bf16 (4 VGPRs)
typedef __attribute__((ext_vector_type(4))) short short4v;   // 4 bf16 (2 VGPRs)
typedef __attribute__((ext_vector_type(4))) float float4v;   // 4 fp32 acc
#define MFMA16 __builtin_amdgcn_mfma_f32_16x16x32_bf16

__device__ __forceinline__ float us2f(unsigned short u) {
  union { unsigned u; float f; } c; c.u = ((unsigned)u) << 16; return c.f;
}
__device__ __forceinline__ unsigned short f2us(float f) {
  return __bfloat16_as_ushort(__float2bfloat16(f));
}

// fp32 x . fp32 w, K % 8 == 0, 16B-aligned
__device__ __forceinline__ float dot_ff(const float* __restrict__ x,
                                        const float* __restrict__ w, int K) {
  const float4* xp = reinterpret_cast<const float4*>(x);
  const float4* wp = reinterpret_cast<const float4*>(w);
  float acc = 0.f;
  const int n = K >> 2;
  for (int i = 0; i < n; ++i) {
    float4 a = xp[i], b = wp[i];
    acc += a.x*b.x + a.y*b.y + a.z*b.z + a.w*b.w;
  }
  return acc;
}

// native-exp sigmoid / tanh (clamped; serial-path hot in GRU)
__device__ __forceinline__ float sigm(float x) { return 1.f / (1.f + __expf(-x)); }
__device__ __forceinline__ float tanh_fast(float x) {
  x = fminf(fmaxf(x, -15.f), 15.f);
  float e = __expf(2.f * x);
  return (e - 1.f) / (e + 1.f);
}

// ---------------------------------------------------------------------------
__global__ void k_canary(float* __restrict__ out) {
  out[blockIdx.x * 256 + threadIdx.x] = 100.0f;
}

// ---------------------------------------------------------------------------
// One-shot: convert MFMA-consumed weights to bf16 in ws.
// ---------------------------------------------------------------------------
__global__ __launch_bounds__(256) void k_cvt(
    const float* __restrict__ a_in_w, const float* __restrict__ t_in_w,
    const float* __restrict__ t_out_w, const float* __restrict__ t_ff1w,
    const float* __restrict__ t_ff2w, const float* __restrict__ a_out_w,
    unsigned short* __restrict__ awb, unsigned short* __restrict__ twb,
    unsigned short* __restrict__ pwb, unsigned short* __restrict__ f1wb,
    unsigned short* __restrict__ f2wb, unsigned short* __restrict__ awb2)
{
  int i = blockIdx.x * 256 + threadIdx.x;
  if (i < 49152)  awb[i] = f2us(a_in_w[i]);
  if (i < 786432) twb[i] = f2us(t_in_w[i]);
  if (i < 262144) pwb[i] = f2us(t_out_w[i]);
  if (i < 524288) f1wb[i] = f2us(t_ff1w[i]);
  if (i < 524288) f2wb[i] = f2us(t_ff2w[i]);
  if (i < 16384)  awb2[i] = f2us(a_out_w[i]);
}

// ---------------------------------------------------------------------------
// GRU weight prep: row-major bf16 copies. whhb [dir][768][256],
// wihb [dir][768][128] (for gi GEMM).
// ---------------------------------------------------------------------------
__global__ __launch_bounds__(256) void k_gru_wb(
    const float* __restrict__ wih_f, const float* __restrict__ whh_f,
    const float* __restrict__ wih_b, const float* __restrict__ whh_b,
    unsigned short* __restrict__ whhb, unsigned short* __restrict__ wihb)
{
  int i = blockIdx.x * 256 + threadIdx.x;   // < 393216
  if (i >= 393216) return;
  int dir = i / 196608, r = i % 196608;
  whhb[i] = f2us((dir ? whh_b : whh_f)[r]);
  if (r < 98304) wihb[dir * 98304 + r] = f2us((dir ? wih_b : wih_f)[r]);
}

// ---------------------------------------------------------------------------
// QKV precompute over the VOCAB. qkt[49689][256] = q,k with bias;
// vt[49689][128] = v with bias. M=32 rows/block, grid 1553.
// ---------------------------------------------------------------------------
__global__ __launch_bounds__(256, 2) void k_qkvpre(
    const float* __restrict__ emb, const unsigned short* __restrict__ awb,
    const float* __restrict__ in_b,
    unsigned short* __restrict__ qkt, unsigned short* __restrict__ vt)
{
  const int row0 = blockIdx.x * 32, tid = threadIdx.x;
  __shared__ alignas(16) unsigned short xs[32 * 136];
  for (int i = tid; i < 1024; i += 256) {
    int t = i >> 5, c4 = (i & 31) << 2;
    int grow = row0 + t; if (grow > 49688) grow = 49688;
    float4 e4 = *reinterpret_cast<const float4*>(emb + (size_t)grow * 128 + c4);
    short4v s; s[0] = f2us(e4.x); s[1] = f2us(e4.y); s[2] = f2us(e4.z); s[3] = f2us(e4.w);
    *reinterpret_cast<short4v*>(xs + t * 136 + c4) = s;
  }
  __syncthreads();
  const int lane = tid & 63, wave = tid >> 6;
  const int l15 = lane & 15, quad = lane >> 4;
  short8v af[2][4];
#pragma unroll
  for (int mt = 0; mt < 2; ++mt)
#pragma unroll
    for (int kc = 0; kc < 4; ++kc)
      af[mt][kc] = *reinterpret_cast<const short8v*>(
          xs + (mt * 16 + l15) * 136 + kc * 32 + quad * 8);
  for (int ni = 0; ni < 6; ++ni) {
    const int j = (wave + ni * 4) * 16 + l15;
    const unsigned short* wrow = awb + (size_t)j * 128;
    float4v acc0 = {0.f, 0.f, 0.f, 0.f}, acc1 = {0.f, 0.f, 0.f, 0.f};
#pragma unroll
    for (int kc = 0; kc < 4; ++kc) {
      short8v bfr = *reinterpret_cast<const short8v*>(wrow + kc * 32 + quad * 8);
      acc0 = MFMA16(af[0][kc], bfr, acc0, 0, 0, 0);
      acc1 = MFMA16(af[1][kc], bfr, acc1, 0, 0, 0);
    }
    const float bj = in_b[j];
#pragma unroll
    for (int r = 0; r < 4; ++r) {
      int g0 = row0 + quad * 4 + r, g1 = g0 + 16;
      if (j < 256) {
        if (g0 <= 49688) qkt[(size_t)g0 * 256 + j] = f2us(acc0[r] + bj);
        if (g1 <= 49688) qkt[(size_t)g1 * 256 + j] = f2us(acc1[r] + bj);
      } else {
        int jj = j - 256;
        if (g0 <= 49688) vt[(size_t)g0 * 128 + jj] = f2us(acc0[r] + bj);
        if (g1 <= 49688) vt[(size_t)g1 * 128 + jj] = f2us(acc1[r] + bj);
      }
    }
  }
}

// ---------------------------------------------------------------------------
// Stage 1: gather precomputed q/k/vT + fused attention + proj-then-mean.
// v-transpose scatter remapped: lane index -> t (contiguous shorts per
// wave), so writes spread across banks (~4-way instead of 16-way; the R16
// stride-40 padding was a wrong fix: c8*stride = 0 mod 64 shorts for both
// 32 and 40, so the WRITE pattern never changed). vTb back to stride 32.
// LDS: qb 8704 (O overlay) + kb 8704 (P overlay) + vTb 8192 = 25,600 B
// -> 5+ blocks/CU.
// ---------------------------------------------------------------------------
__global__ __launch_bounds__(256, 5) void k_order_attn(
    const int* __restrict__ oh, const unsigned short* __restrict__ qkt,
    const unsigned short* __restrict__ vt,
    const unsigned short* __restrict__ awb2, const float* __restrict__ out_b,
    unsigned short* __restrict__ oeb)
{
  const int bo = blockIdx.x;            // 0..8191
  const int tid = threadIdx.x;
  __shared__ alignas(16) unsigned short qb[32 * 136];     // q -> O
  __shared__ alignas(16) unsigned short kb[32 * 136];     // k -> P [128][32]
  __shared__ alignas(16) unsigned short vTb[128 * 32];    // vT[d][t]
  unsigned short* ob = qb;
  unsigned short* pb = kb;

  const int lane = tid & 63, wave = tid >> 6;
  const int l15 = lane & 15, quad = lane >> 4;

  // gather q,k (16B/lane, 512B contiguous per token)
  for (int i = tid; i < 1024; i += 256) {
    int t = i >> 5, c8 = (i & 31) << 3;
    int id = oh[bo * 32 + t];
    short8v v8 = *reinterpret_cast<const short8v*>(qkt + (size_t)id * 256 + c8);
    if (c8 < 128) *reinterpret_cast<short8v*>(qb + t * 136 + c8) = v8;
    else          *reinterpret_cast<short8v*>(kb + t * 136 + (c8 - 128)) = v8;
  }
  // gather v, transpose into vTb: lane->t mapping (bank-friendly writes:
  // for fixed j2 a wave writes addresses const + t -> ~4-way conflict)
  for (int i = tid; i < 512; i += 256) {
    int t = i & 31, c8 = (i >> 5) << 3;
    int id = oh[bo * 32 + t];
    short8v v8 = *reinterpret_cast<const short8v*>(vt + (size_t)id * 128 + c8);
#pragma unroll
    for (int j2 = 0; j2 < 8; ++j2) vTb[(c8 + j2) * 32 + t] = v8[j2];
  }
  __syncthreads();
  // ---- FUSED: scores + exp + PV + ones-rowsum + O write (wave = head) ----
  {
    const int h = wave;
    const float scale1 = 0.17677669529663687f;            // 1/sqrt(32)
    short8v qf[2], kf[2];
#pragma unroll
    for (int mt = 0; mt < 2; ++mt)
      qf[mt] = *reinterpret_cast<const short8v*>(qb + (mt * 16 + l15) * 136 + h * 32 + quad * 8);
#pragma unroll
    for (int nt = 0; nt < 2; ++nt)
      kf[nt] = *reinterpret_cast<const short8v*>(kb + (nt * 16 + l15) * 136 + h * 32 + quad * 8);
    float4v sacc[2][2];
#pragma unroll
    for (int mt = 0; mt < 2; ++mt)
#pragma unroll
      for (int nt = 0; nt < 2; ++nt) {
        sacc[mt][nt] = (float4v){0.f, 0.f, 0.f, 0.f};
        sacc[mt][nt] = MFMA16(qf[mt], kf[nt], sacc[mt][nt], 0, 0, 0);
      }
    __syncthreads();                     // all qb/kb reg-reads done -> P/O writes ok
    // P = exp(s) (no max subtraction: |s| <~ 2, safe)
#pragma unroll
    for (int mt = 0; mt < 2; ++mt)
#pragma unroll
      for (int r = 0; r < 4; ++r) {
        float e0 = __expf(sacc[mt][0][r] * scale1);
        float e1 = __expf(sacc[mt][1][r] * scale1);
        int row = h * 32 + mt * 16 + quad * 4 + r;
        pb[row * 32 + l15] = f2us(e0);
        pb[row * 32 + 16 + l15] = f2us(e1);
      }
    // ones fragment for rowsum MFMA
    short8v ones;
#pragma unroll
    for (int i = 0; i < 8; ++i) ones[i] = (short)0x3F80;  // bf16 1.0
    short8v pf[2], vf[2];
#pragma unroll
    for (int mt = 0; mt < 2; ++mt)
      pf[mt] = *reinterpret_cast<const short8v*>(pb + (h * 32 + mt * 16 + l15) * 32 + quad * 8);
    float4v sums[2];
#pragma unroll
    for (int mt = 0; mt < 2; ++mt) {
      sums[mt] = (float4v){0.f, 0.f, 0.f, 0.f};
      sums[mt] = MFMA16(pf[mt], ones, sums[mt], 0, 0, 0);  // rowsums in C layout
    }
#pragma unroll
    for (int nt = 0; nt < 2; ++nt)
      vf[nt] = *reinterpret_cast<const short8v*>(vTb + (h * 32 + nt * 16 + l15) * 32 + quad * 8);
    float4v oacc[2][2];
#pragma unroll
    for (int mt = 0; mt < 2; ++mt)
#pragma unroll
      for (int nt = 0; nt < 2; ++nt) {
        oacc[mt][nt] = (float4v){0.f, 0.f, 0.f, 0.f};
        oacc[mt][nt] = MFMA16(pf[mt], vf[nt], oacc[mt][nt], 0, 0, 0);
      }
    // write O bf16 into ob (qb overlay): this wave's head-col stripe
#pragma unroll
    for (int mt = 0; mt < 2; ++mt)
#pragma unroll
      for (int r = 0; r < 4; ++r) {
        int t = mt * 16 + quad * 4 + r;
        float inv = 1.f / sums[mt][r];
#pragma unroll
        for (int nt = 0; nt < 2; ++nt)
          ob[t * 136 + h * 32 + nt * 16 + l15] = f2us(oacc[mt][nt][r] * inv);
      }
  }
  __syncthreads();
  // ---- out-proj MFMA: proj[t][j] = O[t][.] . W[j][.]; then mean over t ----
  {
    float4v acc[2][2];
#pragma unroll
    for (int mt = 0; mt < 2; ++mt)
#pragma unroll
      for (int nt = 0; nt < 2; ++nt) acc[mt][nt] = (float4v){0.f, 0.f, 0.f, 0.f};
#pragma unroll
    for (int kc = 0; kc < 4; ++kc) {
      short8v af0 = *reinterpret_cast<const short8v*>(ob + l15 * 136 + kc * 32 + quad * 8);
      short8v af1 = *reinterpret_cast<const short8v*>(ob + (16 + l15) * 136 + kc * 32 + quad * 8);
#pragma unroll
      for (int nt = 0; nt < 2; ++nt) {
        int j = (wave * 2 + nt) * 16 + l15;
        short8v bfr = *reinterpret_cast<const short8v*>(awb2 + (size_t)j * 128 + kc * 32 + quad * 8);
        acc[0][nt] = MFMA16(af0, bfr, acc[0][nt], 0, 0, 0);
        acc[1][nt] = MFMA16(af1, bfr, acc[1][nt], 0, 0, 0);
      }
    }
#pragma unroll
    for (int nt = 0; nt < 2; ++nt) {
      float part = 0.f;
#pragma unroll
      for (int mt = 0; mt < 2; ++mt)
#pragma unroll
        for (int r = 0; r < 4; ++r) part += acc[mt][nt][r];
      part += __shfl_xor(part, 16);
      part += __shfl_xor(part, 32);
      if (quad == 0) {
        int j = (wave * 2 + nt) * 16 + l15;
        oeb[(size_t)bo * 128 + j] = f2us(part * (1.f / 32.f) + out_b[j]);
      }
    }
  }
}

// ---------------------------------------------------------------------------
// gi GEMM (MFMA): gi[8192][1536] bf16 = oe @ wih^T (both dirs). oe is bf16.
// ---------------------------------------------------------------------------
__global__ __launch_bounds__(256, 2) void k_gru_gi(
    const unsigned short* __restrict__ oeb, const unsigned short* __restrict__ wihb,
    unsigned short* __restrict__ gi)
{
  const int row0 = blockIdx.x * 32, tid = threadIdx.x;
  __shared__ alignas(16) unsigned short xs[32 * 136];
  for (int i = tid; i < 512; i += 256) {
    int t = i >> 4, c8 = (i & 15) << 3;
    *reinterpret_cast<short8v*>(xs + t * 136 + c8) =
        *reinterpret_cast<const short8v*>(oeb + (size_t)(row0 + t) * 128 + c8);
  }
  __syncthreads();
  const int lane = tid & 63, wave = tid >> 6;
  const int l15 = lane & 15, quad = lane >> 4;
  short8v af[2][4];
#pragma unroll
  for (int mt = 0; mt < 2; ++mt)
#pragma unroll
    for (int kc = 0; kc < 4; ++kc)
      af[mt][kc] = *reinterpret_cast<const short8v*>(
          xs + (mt * 16 + l15) * 136 + kc * 32 + quad * 8);
  for (int ni = 0; ni < 24; ++ni) {
    int col = (wave + ni * 4) * 16 + l15;
    const unsigned short* wrow = wihb + (size_t)col * 128;
    float4v a0 = {0.f,0.f,0.f,0.f}, a1 = {0.f,0.f,0.f,0.f};
#pragma unroll
    for (int kc = 0; kc < 4; ++kc) {
      short8v bfr = *reinterpret_cast<const short8v*>(wrow + kc * 32 + quad * 8);
      a0 = MFMA16(af[0][kc], bfr, a0, 0, 0, 0);
      a1 = MFMA16(af[1][kc], bfr, a1, 0, 0, 0);
    }
#pragma unroll
    for (int r = 0; r < 4; ++r) {
      gi[(size_t)(row0 + quad * 4 + r) * 1536 + col] = f2us(a0[r]);
      gi[(size_t)(row0 + quad * 4 + r + 16) * 1536 + col] = f2us(a1[r]);
    }
  }
}

// ---------------------------------------------------------------------------
// GRU recurrence via MFMA. 2 batches/block, grid (128,2) = 256 blocks,
// 512 threads (8 waves). whh register-resident. gi prefetched.
// LDS: hb 8448 + pg 6176 = 14,624 B.
// ---------------------------------------------------------------------------
__global__ __launch_bounds__(512, 2) void k_gru_rec(
    const unsigned short* __restrict__ gi, const unsigned short* __restrict__ whhb,
    const float* __restrict__ bih_f, const float* __restrict__ bhh_f,
    const float* __restrict__ bih_b, const float* __restrict__ bhh_b,
    float* __restrict__ g)
{
  const int b0 = blockIdx.x * 2, dir = blockIdx.y;
  const int tid = threadIdx.x;           // 0..511
  const unsigned short* wb = whhb + (size_t)dir * 196608;   // [768][256] bf16
  const float* bih = dir ? bih_b : bih_f;
  const float* bhh = dir ? bhh_b : bhh_f;
  __shared__ alignas(16) unsigned short hb[16 * 264];   // h bf16 (A operand)
  __shared__ float pg[2 * 772];                         // gh fp32 (rows 0-1)
  const int lane = tid & 63, wave = tid >> 6;
  const int l15 = lane & 15, quad = lane >> 4;
  const int j = tid & 255, mb = tid >> 8;               // pointwise: (m=mb, j)
  const float bir = bih[j], biz = bih[256 + j], bin_ = bih[512 + j];
  const float bhr = bhh[j], bhz = bhh[256 + j], bhn  = bhh[512 + j];
  short8v wf[6][8];
  int cols[6];
#pragma unroll
  for (int ni = 0; ni < 6; ++ni) {
    cols[ni] = (wave + ni * 8) * 16 + l15;
#pragma unroll
    for (int kc = 0; kc < 8; ++kc)
      wf[ni][kc] = *reinterpret_cast<const short8v*>(
          wb + (size_t)cols[ni] * 256 + kc * 32 + quad * 8);
  }
  for (int i = tid; i < 16 * 264; i += 512) hb[i] = 0;
  int tcur = dir ? 31 : 0;
  size_t gbase = ((size_t)(b0 + mb) * 32 + tcur) * 1536 + dir * 768;
  float gr = us2f(gi[gbase + j]);
  float gz = us2f(gi[gbase + 256 + j]);
  float gn = us2f(gi[gbase + 512 + j]);
  __syncthreads();
  for (int s = 0; s < 32; ++s) {
    float4v acc[6];
#pragma unroll
    for (int ni = 0; ni < 6; ++ni) acc[ni] = (float4v){0.f, 0.f, 0.f, 0.f};
#pragma unroll
    for (int kc = 0; kc < 8; ++kc) {
      short8v af = *reinterpret_cast<const short8v*>(hb + l15 * 264 + kc * 32 + quad * 8);
#pragma unroll
      for (int ni = 0; ni < 6; ++ni)
        acc[ni] = MFMA16(af, wf[ni][kc], acc[ni], 0, 0, 0);
    }
    if (quad == 0) {
#pragma unroll
      for (int ni = 0; ni < 6; ++ni) {
        pg[cols[ni]] = acc[ni][0];
        pg[772 + cols[ni]] = acc[ni][1];
      }
    }
    float gr2 = 0.f, gz2 = 0.f, gn2 = 0.f;
    if (s < 31) {
      int t2 = dir ? (30 - s) : (s + 1);
      size_t gb2 = ((size_t)(b0 + mb) * 32 + t2) * 1536 + dir * 768;
      gr2 = us2f(gi[gb2 + j]);
      gz2 = us2f(gi[gb2 + 256 + j]);
      gn2 = us2f(gi[gb2 + 512 + j]);
    }
    __syncthreads();
    {
      const int tt = dir ? (31 - s) : s;
      float hprev = us2f(hb[mb * 264 + j]);
      float r = sigm(gr + bir + pg[mb * 772 + j] + bhr);
      float z = sigm(gz + biz + pg[mb * 772 + 256 + j] + bhz);
      float n = tanh_fast(gn + bin_ + r * (pg[mb * 772 + 512 + j] + bhn));
      float nh = (1.f - z) * n + z * hprev;
      hb[mb * 264 + j] = f2us(nh);
      g[((size_t)(b0 + mb) * 32 + tt) * 512 + dir * 256 + j] = nh;
    }
    gr = gr2; gz = gz2; gn = gn2;
    __syncthreads();
  }
}

// ---------------------------------------------------------------------------
// Stage 3 fused attention, one block per (b, head). x staged in K=128
// quarter-chunks (xs3 8,704 B) -> LDS 36,352 B -> 4 blocks/CU.
// ---------------------------------------------------------------------------
__global__ __launch_bounds__(256, 4) void k_mha2f(
    const float* __restrict__ g, const unsigned short* __restrict__ twb,
    const float* __restrict__ Bv, float* __restrict__ attn)
{
  const int b = blockIdx.x, h = blockIdx.y, tid = threadIdx.x;
  __shared__ alignas(16) unsigned short xs3[32 * 136];     // x chunk; P overlay
  __shared__ alignas(16) unsigned short qk[2 * 32 * 136];
  __shared__ alignas(16) unsigned short vT[128 * 40];      // vT[d][k]
  unsigned short* qs = qk;
  unsigned short* ks = qk + 32 * 136;
  unsigned short* pb = xs3;                                // P bf16 [32][32]
  const int lane = tid & 63, wave = tid >> 6;
  const int l15 = lane & 15, quad = lane >> 4;

  int wrowi[6];
#pragma unroll
  for (int ni = 0; ni < 6; ++ni) {
    int idx = (wave + ni * 4) * 16 + l15;
    int m = idx >> 7, dd = idx & 127;
    wrowi[ni] = m * 512 + h * 128 + dd;
  }
  float4v acc[6][2];
#pragma unroll
  for (int ni = 0; ni < 6; ++ni)
#pragma unroll
    for (int mt = 0; mt < 2; ++mt) acc[ni][mt] = (float4v){0.f, 0.f, 0.f, 0.f};

  for (int ck = 0; ck < 4; ++ck) {
    __syncthreads();
    for (int i = tid; i < 1024; i += 256) {                // x quarter load
      int t = i >> 5, c4 = (i & 31) << 2;
      float4 e4 = *reinterpret_cast<const float4*>(
          g + (size_t)b * 16384 + t * 512 + ck * 128 + c4);
      short4v s; s[0] = f2us(e4.x); s[1] = f2us(e4.y); s[2] = f2us(e4.z); s[3] = f2us(e4.w);
      *reinterpret_cast<short4v*>(xs3 + t * 136 + c4) = s;
    }
    __syncthreads();
    short8v af2[2][4];
#pragma unroll
    for (int mt = 0; mt < 2; ++mt)
#pragma unroll
      for (int u = 0; u < 4; ++u)
        af2[mt][u] = *reinterpret_cast<const short8v*>(
            xs3 + (mt * 16 + l15) * 136 + u * 32 + quad * 8);
#pragma unroll
    for (int ni = 0; ni < 6; ++ni) {
      const unsigned short* wrow = twb + (size_t)wrowi[ni] * 512 + ck * 128;
#pragma unroll
      for (int u = 0; u < 4; ++u) {
        short8v bfr = *reinterpret_cast<const short8v*>(wrow + u * 32 + quad * 8);
        acc[ni][0] = MFMA16(af2[0][u], bfr, acc[ni][0], 0, 0, 0);
        acc[ni][1] = MFMA16(af2[1][u], bfr, acc[ni][1], 0, 0, 0);
      }
    }
  }
  __syncthreads();                                         // xs3 reads done
#pragma unroll
  for (int ni = 0; ni < 6; ++ni) {
    int idx = (wave + ni * 4) * 16 + l15;
    int m = idx >> 7, dd = idx & 127;
    float bj = Bv[wrowi[ni]];
    if (m < 2) {
      unsigned short* dst = (m == 0) ? qs : ks;
#pragma unroll
      for (int r = 0; r < 4; ++r) {
        int t0 = quad * 4 + r;
        dst[t0 * 136 + dd] = f2us(acc[ni][0][r] + bj);
        dst[(t0 + 16) * 136 + dd] = f2us(acc[ni][1][r] + bj);
      }
    } else {
      short4v s0, s1;
#pragma unroll
      for (int r = 0; r < 4; ++r) { s0[r] = f2us(acc[ni][0][r] + bj); s1[r] = f2us(acc[ni][1][r] + bj); }
      *reinterpret_cast<short4v*>(vT + dd * 40 + quad * 4) = s0;
      *reinterpret_cast<short4v*>(vT + dd * 40 + 16 + quad * 4) = s1;
    }
  }
  __syncthreads();
  // ---- scores MFMA -> P = exp(s) bf16 directly (no max: |s| <~ 7) ----
  {
    const float scale2 = 0.08838834764831845f;            // 1/sqrt(128)
    const int mt = wave >> 1, nt = wave & 1;
    float4v a = {0.f, 0.f, 0.f, 0.f};
#pragma unroll
    for (int kc = 0; kc < 4; ++kc) {
      short8v qf = *reinterpret_cast<const short8v*>(qs + (mt * 16 + l15) * 136 + kc * 32 + quad * 8);
      short8v kf = *reinterpret_cast<const short8v*>(ks + (nt * 16 + l15) * 136 + kc * 32 + quad * 8);
      a = MFMA16(qf, kf, a, 0, 0, 0);
    }
#pragma unroll
    for (int r = 0; r < 4; ++r) {
      int row = mt * 16 + quad * 4 + r;
      pb[row * 32 + nt * 16 + l15] = f2us(__expf(a[r] * scale2));
    }
  }
  __syncthreads();
  // ---- PV MFMA + ones-rowsum; scale by 1/sum in epilogue ----
  {
    short8v ones;
#pragma unroll
    for (int i = 0; i < 8; ++i) ones[i] = (short)0x3F80;  // bf16 1.0
    short8v pf[2], vf[2];
#pragma unroll
    for (int mt = 0; mt < 2; ++mt)
      pf[mt] = *reinterpret_cast<const short8v*>(pb + (mt * 16 + l15) * 32 + quad * 8);
    float4v sums[2];
#pragma unroll
    for (int mt = 0; mt < 2; ++mt) {
      sums[mt] = (float4v){0.f, 0.f, 0.f, 0.f};
      sums[mt] = MFMA16(pf[mt], ones, sums[mt], 0, 0, 0);
    }
#pragma unroll
    for (int ntl = 0; ntl < 2; ++ntl)
      vf[ntl] = *reinterpret_cast<const short8v*>(vT + ((2 * wave + ntl) * 16 + l15) * 40 + quad * 8);
    float4v oacc[2][2];
#pragma unroll
    for (int mt = 0; mt < 2; ++mt)
#pragma unroll
      for (int ntl = 0; ntl < 2; ++ntl) {
        oacc[mt][ntl] = (float4v){0.f, 0.f, 0.f, 0.f};
        oacc[mt][ntl] = MFMA16(pf[mt], vf[ntl], oacc[mt][ntl], 0, 0, 0);
      }
#pragma unroll
    for (int mt = 0; mt < 2; ++mt)
#pragma unroll
      for (int r = 0; r < 4; ++r) {
        int q = mt * 16 + quad * 4 + r;
        float inv = 1.f / sums[mt][r];
#pragma unroll
        for (int ntl = 0; ntl < 2; ++ntl)
          attn[((size_t)b * 32 + q) * 512 + h * 128 + (2 * wave + ntl) * 16 + l15] =
              oacc[mt][ntl][r] * inv;
      }
  }
}

// ---------------------------------------------------------------------------
// proj GEMM raw, M=32/block (grid 256), 1024 threads (16 waves).
// Writes praw = X @ W^T + bias (fp32); residual+LN by k_resln.
// ---------------------------------------------------------------------------
__global__ __launch_bounds__(1024, 1) void k_proj(
    const float* __restrict__ X, const unsigned short* __restrict__ Wb,
    const float* __restrict__ bias, float* __restrict__ praw)
{
  const int row0 = blockIdx.x * 32, tid = threadIdx.x;
  __shared__ alignas(16) unsigned short xs[32 * 520];
  const int lane = tid & 63, wave = tid >> 6;             // wave 0..15
  const int l15 = lane & 15, quad = lane >> 4;
  for (int i = tid; i < 4096; i += 1024) {
    int t = i >> 7, c4 = (i & 127) << 2;
    float4 e4 = *reinterpret_cast<const float4*>(X + (size_t)(row0 + t) * 512 + c4);
    short4v s; s[0] = f2us(e4.x); s[1] = f2us(e4.y); s[2] = f2us(e4.z); s[3] = f2us(e4.w);
    *reinterpret_cast<short4v*>(xs + t * 520 + c4) = s;
  }
  __syncthreads();
#pragma unroll
  for (int ni = 0; ni < 2; ++ni) {
    const int col = (wave + ni * 16) * 16 + l15;
    const unsigned short* wrow = Wb + (size_t)col * 512;
    float4v a0 = {0.f,0.f,0.f,0.f}, a1 = {0.f,0.f,0.f,0.f};
#pragma unroll
    for (int kc = 0; kc < 16; ++kc) {
      short8v b = *reinterpret_cast<const short8v*>(wrow + kc * 32 + quad * 8);
      short8v x0 = *reinterpret_cast<const short8v*>(xs + l15 * 520 + kc * 32 + quad * 8);
      short8v x1 = *reinterpret_cast<const short8v*>(xs + (16 + l15) * 520 + kc * 32 + quad * 8);
      a0 = MFMA16(x0, b, a0, 0, 0, 0);
      a1 = MFMA16(x1, b, a1, 0, 0, 0);
    }
    const float bj = bias[col];
#pragma unroll
    for (int r = 0; r < 4; ++r) {
      praw[(size_t)(row0 + quad * 4 + r) * 512 + col] = a0[r] + bj;
      praw[(size_t)(row0 + 16 + quad * 4 + r) * 512 + col] = a1[r] + bj;
    }
  }
}

// ---------------------------------------------------------------------------
// FF pair, M=32/block (grid 256), 1024 threads (16 waves).
// 4 chunks of 256 f1-cols. f1 chunk in LDS, ff2 accumulates each K-chunk
// into persistent regs. Writes yraw (fp32).
// LDS: xs 33,280 + f1c 16,896 = 50,176 B.
// ---------------------------------------------------------------------------
__global__ __launch_bounds__(1024, 1) void k_ff(
    const float* __restrict__ X, const unsigned short* __restrict__ W1,
    const float* __restrict__ b1, const unsigned short* __restrict__ W2,
    const float* __restrict__ b2, float* __restrict__ yraw)
{
  const int row0 = blockIdx.x * 32, tid = threadIdx.x;
  __shared__ alignas(16) unsigned short xs[32 * 520];     // X bf16 [32][520]
  __shared__ alignas(16) unsigned short f1c[32 * 264];    // f1 chunk [32][264]
  const int lane = tid & 63, wave = tid >> 6;             // wave 0..15
  const int l15 = lane & 15, quad = lane >> 4;
  for (int i = tid; i < 4096; i += 1024) {                // X load (float4)
    int t = i >> 7, c4 = (i & 127) << 2;
    float4 e4 = *reinterpret_cast<const float4*>(X + (size_t)(row0 + t) * 512 + c4);
    short4v s; s[0] = f2us(e4.x); s[1] = f2us(e4.y); s[2] = f2us(e4.z); s[3] = f2us(e4.w);
    *reinterpret_cast<short4v*>(xs + t * 520 + c4) = s;
  }
  __syncthreads();
  float4v acc2[2][2];                                     // ff2 accum (persist)
#pragma unroll
  for (int mt = 0; mt < 2; ++mt)
#pragma unroll
    for (int ni = 0; ni < 2; ++ni) acc2[mt][ni] = (float4v){0.f,0.f,0.f,0.f};
  int cols2[2];
#pragma unroll
  for (int ni = 0; ni < 2; ++ni) cols2[ni] = (wave + ni * 16) * 16 + l15;

  for (int ck = 0; ck < 4; ++ck) {                        // 4 chunks of 256 f1-cols
    // ---- ff1 for this chunk: col = ck*256 + wave*16 + l15 ----
    {
      const int col = ck * 256 + wave * 16 + l15;
      const unsigned short* wrow = W1 + (size_t)col * 512;
      float4v a0 = {0.f,0.f,0.f,0.f}, a1 = {0.f,0.f,0.f,0.f};
#pragma unroll
      for (int kc = 0; kc < 16; ++kc) {
        short8v b = *reinterpret_cast<const short8v*>(wrow + kc * 32 + quad * 8);
        short8v x0 = *reinterpret_cast<const short8v*>(xs + l15 * 520 + kc * 32 + quad * 8);
        short8v x1 = *reinterpret_cast<const short8v*>(xs + (16 + l15) * 520 + kc * 32 + quad * 8);
        a0 = MFMA16(x0, b, a0, 0, 0, 0);
        a1 = MFMA16(x1, b, a1, 0, 0, 0);
      }
      const float bj = b1[col];
      const int cl = wave * 16 + l15;                     // chunk-local col
#pragma unroll
      for (int r = 0; r < 4; ++r) {
        f1c[(quad * 4 + r) * 264 + cl] = f2us(fmaxf(a0[r] + bj, 0.f));
        f1c[(16 + quad * 4 + r) * 264 + cl] = f2us(fmaxf(a1[r] + bj, 0.f));
      }
    }
    __syncthreads();
    // ---- ff2 accumulate this K-chunk (256 elems = 8 kc) ----
#pragma unroll
    for (int ni = 0; ni < 2; ++ni) {
      const unsigned short* wrow2 = W2 + (size_t)cols2[ni] * 1024 + ck * 256;
#pragma unroll
      for (int kc = 0; kc < 8; ++kc) {
        short8v b = *reinterpret_cast<const short8v*>(wrow2 + kc * 32 + quad * 8);
        short8v a0 = *reinterpret_cast<const short8v*>(f1c + l15 * 264 + kc * 32 + quad * 8);
        short8v a1 = *reinterpret_cast<const short8v*>(f1c + (16 + l15) * 264 + kc * 32 + quad * 8);
        acc2[0][ni] = MFMA16(a0, b, acc2[0][ni], 0, 0, 0);
        acc2[1][ni] = MFMA16(a1, b, acc2[1][ni], 0, 0, 0);
      }
    }
    __syncthreads();                                      // f1c reusable
  }
  // ---- epilogue: yraw = ff2 + bias (fp32) ----
#pragma unroll
  for (int mt = 0; mt < 2; ++mt)
#pragma unroll
    for (int ni = 0; ni < 2; ++ni) {
      int col = cols2[ni];
      float bj = b2[col];
#pragma unroll
      for (int r = 0; r < 4; ++r)
        yraw[(size_t)(row0 + mt * 16 + quad * 4 + r) * 512 + col] = acc2[mt][ni][r] + bj;
    }
}

// ---------------------------------------------------------------------------
// residual + LN: Y = LN(yraw + res). M=16/block, grid 512, 256 threads.
// ---------------------------------------------------------------------------
__global__ __launch_bounds__(256, 2) void k_resln(
    const float* __restrict__ yraw, const float* __restrict__ res,
    const float* __restrict__ gam, const float* __restrict__ bet,
    float* __restrict__ Y)
{
  const int row0 = blockIdx.x * 16, tid = threadIdx.x;
  __shared__ float ys[16 * 516];
  for (int i = tid; i < 16 * 512; i += 256) {
    int t = i >> 9, c = i & 511;
    ys[t * 516 + c] = yraw[(size_t)(row0 + t) * 512 + c] +
                      res[(size_t)(row0 + t) * 512 + c];
  }
  __syncthreads();
  {
    int row = tid >> 4, l16 = tid & 15;
    const float* yr = ys + row * 516;
    float part = 0.f;
#pragma unroll
    for (int k = 0; k < 32; ++k) part += yr[l16 + 16 * k];
#pragma unroll
    for (int off = 8; off; off >>= 1) part += __shfl_xor(part, off, 16);
    float mean = part * (1.f / 512.f);
    float var = 0.f;
#pragma unroll
    for (int k = 0; k < 32; ++k) { float d = yr[l16 + 16 * k] - mean; var += d * d; }
#pragma unroll
    for (int off = 8; off; off >>= 1) var += __shfl_xor(var, off, 16);
    float rs = rsqrtf(var * (1.f / 512.f) + 1e-5f);
    for (int k = 0; k < 32; ++k) {
      int c = l16 + 16 * k;
      Y[(size_t)(row0 + row) * 512 + c] = (yr[c] - mean) * rs * gam[c] + bet[c];
    }
  }
}

// ---------------------------------------------------------------------------
// Final: mean-pool, temporal MLP, concat, classifier, LN, relu -> fp32
// ---------------------------------------------------------------------------
__global__ __launch_bounds__(256) void k_final(
    const float* __restrict__ g2,
    const float* __restrict__ db, const float* __restrict__ dsl,
    const float* __restrict__ te1_w, const float* __restrict__ te1_b,
    const float* __restrict__ l1g, const float* __restrict__ l1b,
    const float* __restrict__ te2_w, const float* __restrict__ te2_b,
    const float* __restrict__ l2g, const float* __restrict__ l2b,
    const float* __restrict__ c_w, const float* __restrict__ c_b,
    const float* __restrict__ clg, const float* __restrict__ clb,
    float* __restrict__ out)
{
  const int b = blockIdx.x, tid = threadIdx.x;
  __shared__ float cat[640];
  __shared__ float t1[64];
  __shared__ float t2[128];
  __shared__ float pre[256];
  __shared__ float red[256];
  __shared__ float st[2];
  for (int i = tid; i < 512; i += 256) {
    float acc = 0.f;
#pragma unroll
    for (int t = 0; t < 32; ++t) acc += g2[((size_t)b * 32 + t) * 512 + i];
    cat[i] = acc * (1.f / 32.f);
  }
  if (tid == 0) {
    float s = 0.f;
    for (int i = 0; i < 31; ++i) s += db[b * 31 + i];
    st[0] = s / 31.f;
    st[1] = dsl[b];
  }
  __syncthreads();
  const float f0 = st[0], f1v = st[1];
  if (tid < 64)
    t1[tid] = f0 * te1_w[tid * 2] + f1v * te1_w[tid * 2 + 1] + te1_b[tid];
  __syncthreads();
  if (tid == 0) {
    float m = 0.f; for (int i = 0; i < 64; ++i) m += t1[i]; m *= (1.f / 64.f);
    float v = 0.f; for (int i = 0; i < 64; ++i) { float d = t1[i] - m; v += d * d; }
    st[0] = m; st[1] = rsqrtf(v * (1.f / 64.f) + 1e-5f);
  }
  __syncthreads();
  if (tid < 64) {
    float v = (t1[tid] - st[0]) * st[1] * l1g[tid] + l1b[tid];
    t1[tid] = fmaxf(v, 0.f);
  }
  __syncthreads();
  if (tid < 128)
    t2[tid] = dot_ff(t1, te2_w + (size_t)tid * 64, 64) + te2_b[tid];
  __syncthreads();
  if (tid == 0) {
    float m = 0.f; for (int i = 0; i < 128; ++i) m += t2[i]; m *= (1.f / 128.f);
    float v = 0.f; for (int i = 0; i < 128; ++i) { float d = t2[i] - m; v += d * d; }
    st[0] = m; st[1] = rsqrtf(v * (1.f / 128.f) + 1e-5f);
  }
  __syncthreads();
  if (tid < 128) {
    float v = (t2[tid] - st[0]) * st[1] * l2g[tid] + l2b[tid];
    cat[512 + tid] = fmaxf(v, 0.f);
  }
  __syncthreads();
  pre[tid] = dot_ff(cat, c_w + (size_t)tid * 640, 640) + c_b[tid];
  red[tid] = pre[tid];
  __syncthreads();
  for (int s = 128; s > 0; s >>= 1) { if (tid < s) red[tid] += red[tid + s]; __syncthreads(); }
  const float m = red[0] * (1.f / 256.f);
  __syncthreads();
  const float d = pre[tid] - m;
  red[tid] = d * d;
  __syncthreads();
  for (int s = 128; s > 0; s >>= 1) { if (tid < s) red[tid] += red[tid + s]; __syncthreads(); }
  const float rs = rsqrtf(red[0] * (1.f / 256.f) + 1e-5f);
  float v = d * rs * clg[tid] + clb[tid];
  out[(size_t)b * 256 + tid] = fmaxf(v, 0.f);
}

// ---------------------------------------------------------------------------
extern "C" void kernel_launch(void* const* d_in, const int* in_sizes, int n_in,
                              void* d_out, int out_size, void* d_ws, size_t ws_size,
                              hipStream_t stream) {
  (void)in_sizes; (void)n_in; (void)out_size; (void)ws_size;
  const int*   oh     = (const int*)  d_in[0];
  const float* db     = (const float*)d_in[1];
  const float* dsl    = (const float*)d_in[2];
  const float* emb    = (const float*)d_in[3];
  const float* a_in_w = (const float*)d_in[4];
  const float* a_in_b = (const float*)d_in[5];
  const float* a_out_w= (const float*)d_in[6];
  const float* a_out_b= (const float*)d_in[7];
  const float* wih_f  = (const float*)d_in[8];
  const float* whh_f  = (const float*)d_in[9];
  const float* bih_f  = (const float*)d_in[10];
  const float* bhh_f  = (const float*)d_in[11];
  const float* wih_b  = (const float*)d_in[12];
  const float* whh_b  = (const float*)d_in[13];
  const float* bih_b  = (const float*)d_in[14];
  const float* bhh_b  = (const float*)d_in[15];
  const float* t_in_w = (const float*)d_in[16];
  const float* t_in_b = (const float*)d_in[17];
  const float* t_out_w= (const float*)d_in[18];
  const float* t_out_b= (const float*)d_in[19];
  const float* t_ln1g = (const float*)d_in[20];
  const float* t_ln1b = (const float*)d_in[21];
  const float* t_ff1w = (const float*)d_in[22];
  const float* t_ff1b = (const float*)d_in[23];
  const float* t_ff2w = (const float*)d_in[24];
  const float* t_ff2b = (const float*)d_in[25];
  const float* t_ln2g = (const float*)d_in[26];
  const float* t_ln2b = (const float*)d_in[27];
  const float* te1_w  = (const float*)d_in[28];
  const float* te1_b  = (const float*)d_in[29];
  const float* tl1g   = (const float*)d_in[30];
  const float* tl1b   = (const float*)d_in[31];
  const float* te2_w  = (const float*)d_in[32];
  const float* te2_b  = (const float*)d_in[33];
  const float* tl2g   = (const float*)d_in[34];
  const float* tl2b   = (const float*)d_in[35];
  const float* c_w    = (const float*)d_in[36];
  const float* c_b    = (const float*)d_in[37];
  const float* clng   = (const float*)d_in[38];
  const float* clnb   = (const float*)d_in[39];

  float* ws = (float*)d_ws;
  // Workspace (float slots), max index 17,391,616 (~69.6 MB):
  //   A [0,        524288):  oeb bf16 [8192][128]
  //   B [1048576,  5242880): qkt bf16 (dead after order_attn) -> g fp32
  //       -> yraw fp32 (after resln#1; g dead)
  //   C [5242880,  9437184): attn fp32; g1 resln#1 in-place; g2 resln#2
  //   D [9437184,  9633792): whhb bf16 [2][768][256]
  //   D2[9633792,  9732096): wihb bf16 [2][768][128]
  //   D3[9732096,  9740288): awb2 bf16 [128*128]
  //   E [10027008,10051584): awb bf16 [384*128]
  //   F [10051584,10444800): twb bf16 [1536*512]
  //   G [10444800,10575872): pwb bf16 [512*512]
  //   G2[10575872,10838016): f1wb bf16 [1024*512]
  //   G3[10838016,11100160): f2wb bf16 [512*1024]
  //   H [11100160,17391616): vt bf16 -> gi bf16 (dead after gru_rec)
  //       -> praw fp32 [8192][512] (proj raw)
  unsigned short* oeb  = (unsigned short*)ws;
  unsigned short* qkt  = (unsigned short*)(ws + 1048576);
  float* g    = ws + 1048576;                           // over dead qkt
  float* yraw = ws + 1048576;                           // over dead g (post-resln#1)
  float* attn = ws + 5242880;
  float* g1   = attn;                                   // in-place resln#1 out
  float* g2   = attn;                                   // in-place resln#2 out
  unsigned short* whhb = (unsigned short*)(ws + 9437184);
  unsigned short* wihb = (unsigned short*)(ws + 9633792);
  unsigned short* awb2 = (unsigned short*)(ws + 9732096);
  unsigned short* awb  = (unsigned short*)(ws + 10027008);
  unsigned short* twb  = (unsigned short*)(ws + 10051584);
  unsigned short* pwb  = (unsigned short*)(ws + 10444800);
  unsigned short* f1wb = (unsigned short*)(ws + 10575872);
  unsigned short* f2wb = (unsigned short*)(ws + 10838016);
  unsigned short* vt   = (unsigned short*)(ws + 11100160);
  unsigned short* gi   = (unsigned short*)(ws + 11100160); // over dead vt
  float* praw = ws + 11100160;                          // over dead gi

  k_canary<<<256, 256, 0, stream>>>((float*)d_out);
  k_cvt<<<3072, 256, 0, stream>>>(a_in_w, t_in_w, t_out_w, t_ff1w, t_ff2w, a_out_w,
                                  awb, twb, pwb, f1wb, f2wb, awb2);
  k_gru_wb<<<1536, 256, 0, stream>>>(wih_f, whh_f, wih_b, whh_b, whhb, wihb);
  k_qkvpre<<<1553, 256, 0, stream>>>(emb, awb, a_in_b, qkt, vt);
  k_order_attn<<<8192, 256, 0, stream>>>(oh, qkt, vt, awb2, a_out_b, oeb);
  k_gru_gi<<<256, 256, 0, stream>>>(oeb, wihb, gi);
  k_gru_rec<<<dim3(128, 2), 512, 0, stream>>>(gi, whhb, bih_f, bhh_f, bih_b, bhh_b, g);
  k_mha2f<<<dim3(256, 4), 256, 0, stream>>>(g, twb, t_in_b, attn);
  k_proj<<<256, 1024, 0, stream>>>(attn, pwb, t_out_b, praw);
  k_resln<<<512, 256, 0, stream>>>(praw, g, t_ln1g, t_ln1b, g1);
  k_ff<<<256, 1024, 0, stream>>>(g1, f1wb, t_ff1b, f2wb, t_ff2b, yraw);
  k_resln<<<512, 256, 0, stream>>>(yraw, g1, t_ln2g, t_ln2b, g2);
  k_final<<<256, 256, 0, stream>>>(g2, db, dsl, te1_w, te1_b, tl1g, tl1b,
                                   te2_w, te2_b, tl2g, tl2b, c_w, c_b, clng, clnb,
                                   (float*)d_out);
}